// Round 1
// baseline (25405.424 us; speedup 1.0000x reference)
//
#include <hip/hip_runtime.h>
#include <math.h>

static constexpr int T_SEQ = 1024;
static constexpr int DIN = 128;
static constexpr int HID = 256;
static constexpr int DOUT = 1000;
static constexpr int NB = 128;
static constexpr int SLOT = HID * NB;   // 32768 floats per h slot, [H][B]-major

// LDS layout (floats).
static constexpr int W1STR = 388;              // K=384 + 4
static constexpr int W2STR = 516;              // K=512 + 4
static constexpr int ASTR  = 652;              // [x 0:128 | h1 128:384 | h2 384:640] + 12
static constexpr int OFF_W2 = 16 * W1STR;            // 6208
static constexpr int OFF_A  = OFF_W2 + 16 * W2STR;   // 14464
static constexpr int OFF_Z  = OFF_A + 32 * ASTR;     // 35328: zpart [8 waves][32 b][20]
static constexpr int OFF_B1 = OFF_Z + 8 * 640;       // 40448
static constexpr int OFF_B2 = OFF_B1 + 16;           // 40464
static constexpr size_t SMEM_BYTES = (size_t)(OFF_B2 + 16) * 4;   // 161,920 B (1 block/CU)

typedef float v4f __attribute__((ext_vector_type(4)));
typedef unsigned long long u64t;

#define SCOPE_AGENT __HIP_MEMORY_SCOPE_AGENT

__device__ __forceinline__ int ld_flag(const int* p) {
    return __hip_atomic_load(p, __ATOMIC_RELAXED, SCOPE_AGENT);
}
__device__ __forceinline__ void st_flag(int* p, int v) {
    __hip_atomic_store(p, v, __ATOMIC_RELAXED, SCOPE_AGENT);
}
__device__ __forceinline__ void st_cp4(float* p, float v) {
    __hip_atomic_store(p, v, __ATOMIC_RELAXED, SCOPE_AGENT);
}

union F2U { u64t u; float f[2]; };

__device__ __forceinline__ float dot4(float acc, v4f va, v4f vb) {
    return fmaf(va.x, vb.x, fmaf(va.y, vb.y,
           fmaf(va.z, vb.z, fmaf(va.w, vb.w, acc))));
}

// Fused 2-layer LSTM, 256 blocks x 512 threads, 1 block/CU.
// R9 restructure: per-wave self-contained k-slices.
//   wave0: x cols 0-95            (no poll — x is read-only input)
//   wave1: x 96-127 + h1 units 0-63   (polls flags 0..15)
//   wave2: h1 64-159                  (polls 16..39)
//   wave3: h1 160-255                 (polls 40..63)
//   wave4: h1 0-127  (L2 operand)     (polls 0..31)
//   wave5: h1 128-255                 (polls 32..63)
//   wave6: h2 0-127                   (polls 0..31)
//   wave7: h2 128-255                 (polls 32..63)
// Each wave: poll deps -> acquire fence -> load+ds_write own slice ->
// lgkmcnt(0) -> GEMM own k-slice -> shfl_xor(32) 2-way reduce ->
// ds_write partial to zpart[w].  Only TWO block barriers per phase:
// B3 (partials ready for ew) and B4 (ew done; publish drained before flag).
// h1 LDS cols 128:384 are written by waves 1-3 AND 4-5 with IDENTICAL
// values (same global addresses, post-fence, producers stable until next
// phase) — benign 4B-granular same-value race. No LDS atomics, no z
// zeroing, no z double-buffer (zpart overwrite is fenced by B3/B4).
__global__ __launch_bounds__(512)
void lstm_fused_kernel(const float* __restrict__ x,
                       const float* __restrict__ W1, const float* __restrict__ U1,
                       const float* __restrict__ b1,
                       const float* __restrict__ W2, const float* __restrict__ U2,
                       const float* __restrict__ b2,
                       float* __restrict__ h1b,   // 2*SLOT (d_out scratch), [slot][H][B]
                       float* __restrict__ ws)    // [1024 ints: flags][2*SLOT h2 [H][B]]
{
    extern __shared__ float smem[];
    float* wT1   = smem;
    float* wT2   = smem + OFF_W2;
    float* hsA   = smem + OFF_A;
    float* zpart = smem + OFF_Z;    // [8][32][20]
    float* bia1  = smem + OFF_B1;
    float* bia2  = smem + OFF_B2;

    int*   F   = (int*)ws;          // 4 groups x 128 ints (first 64 used each)
    float* h2b = ws + 1024;

    const int tid = threadIdx.x;
    const int bid = blockIdx.x;
    const int bg  = bid >> 6;       // batch group 0..3 (batches bg*32..+31)
    const int ug  = bid & 63;       // unit group (units ug*4..+3)
    int* grpF = F + bg * 128;
    int* myF  = grpF + ug;

    const int w    = tid >> 6;      // wave 0..7
    const int lane = tid & 63;

    // ---- one-time: both weight tiles (transposed) + biases into LDS ----
    {
        const int half = tid >> 8;          // 0: L1 weights, 1: L2 weights
        const int t    = tid & 255;
        const int K    = half ? 512 : 384;
        const int len0 = half ? 256 : 128;
        const float* Wp = half ? W2 : W1;
        const float* Up = half ? U2 : U1;
        float* wt = half ? wT2 : wT1;
        const int wstr = half ? W2STR : W1STR;
        for (int c = 0; c < 16; ++c) {
            const int col = (c & 3) * HID + ug * 4 + (c >> 2);   // gate-major
            for (int k = t; k < K; k += 256)
                wt[c * wstr + k] = (k < len0) ? Wp[(size_t)k * (4 * HID) + col]
                                              : Up[(size_t)(k - len0) * (4 * HID) + col];
        }
    }
    if (tid < 16)                     bia1[tid] = b1[(tid & 3) * HID + ug * 4 + (tid >> 2)];
    else if (tid >= 256 && tid < 272) { const int t = tid - 256;
                                        bia2[t]  = b2[(t & 3) * HID + ug * 4 + (t >> 2)]; }
    __syncthreads();

    float cst = 0.f;                  // L1 state (tid<128) or L2 state (256<=tid<384)

    for (int p = 0; p <= T_SEQ; ++p) {
        // ================= per-wave stage (poll -> fence -> load -> LDS) ====
        if (w == 0) {
            if (p < T_SEQ) {
                const int r = lane >> 1, cb = (lane & 1) * 12;
                const float* xr = x + ((size_t)(bg * 32 + r) * T_SEQ + p) * DIN;
                float* dst = hsA + r * ASTR;
                #pragma unroll
                for (int i = 0; i < 12; ++i)
                    *(v4f*)(dst + (cb + i) * 4) = *(const v4f*)(xr + (cb + i) * 4);
            }
        } else {
            int lo, cnt, kbase, niter, colbase = 128;
            bool active;
            const float* hb = h1b + (size_t)((p + 1) & 1) * SLOT;
            switch (w) {
              case 1:  lo = 0;  cnt = 16; kbase = 0;   niter = 16; active = (p < T_SEQ); break;
              case 2:  lo = 16; cnt = 24; kbase = 64;  niter = 24; active = (p < T_SEQ); break;
              case 3:  lo = 40; cnt = 24; kbase = 160; niter = 24; active = (p < T_SEQ); break;
              case 4:  lo = 0;  cnt = 32; kbase = 0;   niter = 32; active = (p >= 1); break;
              case 5:  lo = 32; cnt = 32; kbase = 128; niter = 32; active = (p >= 1); break;
              case 6:  lo = 0;  cnt = 32; kbase = 0;   niter = 32; colbase = 384;
                       hb = h2b + (size_t)(p & 1) * SLOT; active = (p >= 1); break;
              default: lo = 32; cnt = 32; kbase = 128; niter = 32; colbase = 384;
                       hb = h2b + (size_t)(p & 1) * SLOT; active = (p >= 1); break;
            }
            const bool doLoad = (w >= 6) ? (p >= 2) : (p >= 1);
            if (active) {
                v4f xv[4];
                if (w == 1) {   // issue x loads before the poll (read-only, cached)
                    const int r = lane >> 1, cb = 24 + (lane & 1) * 4;
                    const float* xr = x + ((size_t)(bg * 32 + r) * T_SEQ + p) * DIN;
                    #pragma unroll
                    for (int i = 0; i < 4; ++i) xv[i] = *(const v4f*)(xr + (cb + i) * 4);
                }
                if (doLoad) {
                    for (;;) {
                        const int li = (lane < cnt) ? lane : (cnt - 1);
                        int a = ld_flag(grpF + lo + li);
                        if (__all(a >= p)) break;
                        __builtin_amdgcn_s_sleep(4);
                    }
                    // REQUIRED: consumer h loads below are cached; invalidate first.
                    __builtin_amdgcn_fence(__ATOMIC_ACQUIRE, "agent");
                }
                const u64t* hp = (const u64t*)(hb + bg * 32);
                for (int i = 0; i < niter; ++i) {
                    const int idx = lane + i * 64;
                    const int kl = idx >> 4, bb = idx & 15;
                    F2U v; v.u = doLoad ? hp[(size_t)(kbase + kl) * 64 + bb] : 0ull;
                    hsA[(bb * 2 + 0) * ASTR + colbase + kbase + kl] = v.f[0];
                    hsA[(bb * 2 + 1) * ASTR + colbase + kbase + kl] = v.f[1];
                }
                if (w == 1) {
                    const int r = lane >> 1, cb = 24 + (lane & 1) * 4;
                    #pragma unroll
                    for (int i = 0; i < 4; ++i)
                        *(v4f*)(hsA + r * ASTR + (cb + i) * 4) = xv[i];
                }
            }
        }
        // wave-local: my ds_writes complete before my ds_reads (cross-lane
        // within the wave via the transpose). rule-18 fence after inline asm.
        asm volatile("s_waitcnt lgkmcnt(0)" ::: "memory");
        __builtin_amdgcn_sched_barrier(0);

        // ================= per-wave GEMM over own k-slice ===================
        {
            const int cq = lane & 3, bq = (lane >> 2) & 7, kh = lane >> 5;
            if (w < 4) {
                if (p < T_SEQ) {
                    const int kb = w * 96 + kh * 48;
                    const float* Ab = hsA + (bq * 4) * ASTR + kb;
                    const float* Wb = wT1 + (cq * 4) * W1STR + kb;
                    float acc[4][4] = {};
                    #pragma unroll
                    for (int j = 0; j < 12; ++j) {
                        v4f a0 = *(const v4f*)(Ab + 0 * ASTR + j * 4);
                        v4f a1 = *(const v4f*)(Ab + 1 * ASTR + j * 4);
                        v4f a2 = *(const v4f*)(Ab + 2 * ASTR + j * 4);
                        v4f a3 = *(const v4f*)(Ab + 3 * ASTR + j * 4);
                        v4f w0 = *(const v4f*)(Wb + 0 * W1STR + j * 4);
                        v4f w1 = *(const v4f*)(Wb + 1 * W1STR + j * 4);
                        v4f w2 = *(const v4f*)(Wb + 2 * W1STR + j * 4);
                        v4f w3 = *(const v4f*)(Wb + 3 * W1STR + j * 4);
                        acc[0][0]=dot4(acc[0][0],a0,w0); acc[0][1]=dot4(acc[0][1],a0,w1);
                        acc[0][2]=dot4(acc[0][2],a0,w2); acc[0][3]=dot4(acc[0][3],a0,w3);
                        acc[1][0]=dot4(acc[1][0],a1,w0); acc[1][1]=dot4(acc[1][1],a1,w1);
                        acc[1][2]=dot4(acc[1][2],a1,w2); acc[1][3]=dot4(acc[1][3],a1,w3);
                        acc[2][0]=dot4(acc[2][0],a2,w0); acc[2][1]=dot4(acc[2][1],a2,w1);
                        acc[2][2]=dot4(acc[2][2],a2,w2); acc[2][3]=dot4(acc[2][3],a2,w3);
                        acc[3][0]=dot4(acc[3][0],a3,w0); acc[3][1]=dot4(acc[3][1],a3,w1);
                        acc[3][2]=dot4(acc[3][2],a3,w2); acc[3][3]=dot4(acc[3][3],a3,w3);
                    }
                    #pragma unroll
                    for (int i = 0; i < 4; ++i)
                        #pragma unroll
                        for (int c = 0; c < 4; ++c)
                            acc[i][c] += __shfl_xor(acc[i][c], 32);
                    if (kh == 0) {
                        float* zp = zpart + w * 640 + (bq * 4) * 20 + cq * 4;
                        #pragma unroll
                        for (int i = 0; i < 4; ++i) {
                            v4f t; t.x = acc[i][0]; t.y = acc[i][1];
                                   t.z = acc[i][2]; t.w = acc[i][3];
                            *(v4f*)(zp + i * 20) = t;
                        }
                    }
                }
            } else {
                if (p >= 1) {
                    const int kb = (w - 4) * 128 + kh * 64;
                    const float* Ab = hsA + (bq * 4) * ASTR + 128 + kb;
                    const float* Wb = wT2 + (cq * 4) * W2STR + kb;
                    float acc[4][4] = {};
                    #pragma unroll
                    for (int j = 0; j < 16; ++j) {
                        v4f a0 = *(const v4f*)(Ab + 0 * ASTR + j * 4);
                        v4f a1 = *(const v4f*)(Ab + 1 * ASTR + j * 4);
                        v4f a2 = *(const v4f*)(Ab + 2 * ASTR + j * 4);
                        v4f a3 = *(const v4f*)(Ab + 3 * ASTR + j * 4);
                        v4f w0 = *(const v4f*)(Wb + 0 * W2STR + j * 4);
                        v4f w1 = *(const v4f*)(Wb + 1 * W2STR + j * 4);
                        v4f w2 = *(const v4f*)(Wb + 2 * W2STR + j * 4);
                        v4f w3 = *(const v4f*)(Wb + 3 * W2STR + j * 4);
                        acc[0][0]=dot4(acc[0][0],a0,w0); acc[0][1]=dot4(acc[0][1],a0,w1);
                        acc[0][2]=dot4(acc[0][2],a0,w2); acc[0][3]=dot4(acc[0][3],a0,w3);
                        acc[1][0]=dot4(acc[1][0],a1,w0); acc[1][1]=dot4(acc[1][1],a1,w1);
                        acc[1][2]=dot4(acc[1][2],a1,w2); acc[1][3]=dot4(acc[1][3],a1,w3);
                        acc[2][0]=dot4(acc[2][0],a2,w0); acc[2][1]=dot4(acc[2][1],a2,w1);
                        acc[2][2]=dot4(acc[2][2],a2,w2); acc[2][3]=dot4(acc[2][3],a2,w3);
                        acc[3][0]=dot4(acc[3][0],a3,w0); acc[3][1]=dot4(acc[3][1],a3,w1);
                        acc[3][2]=dot4(acc[3][2],a3,w2); acc[3][3]=dot4(acc[3][3],a3,w3);
                    }
                    #pragma unroll
                    for (int i = 0; i < 4; ++i)
                        #pragma unroll
                        for (int c = 0; c < 4; ++c)
                            acc[i][c] += __shfl_xor(acc[i][c], 32);
                    if (kh == 0) {
                        float* zp = zpart + w * 640 + (bq * 4) * 20 + cq * 4;
                        #pragma unroll
                        for (int i = 0; i < 4; ++i) {
                            v4f t; t.x = acc[i][0]; t.y = acc[i][1];
                                   t.z = acc[i][2]; t.w = acc[i][3];
                            *(v4f*)(zp + i * 20) = t;
                        }
                    }
                }
            }
        }
        __syncthreads();                                    // B3: partials ready

        // ================= ew + direct publish from registers ===============
        if (tid < 128) {
            if (p < T_SEQ) {
                const int eb = tid & 31, eu = tid >> 5;
                const float* zp = zpart + eb * 20 + eu * 4;
                float zi = bia1[eu*4+0] + zp[0] + zp[640+0] + zp[1280+0] + zp[1920+0];
                float zf = bia1[eu*4+1] + zp[1] + zp[640+1] + zp[1280+1] + zp[1920+1];
                float zg = bia1[eu*4+2] + zp[2] + zp[640+2] + zp[1280+2] + zp[1920+2];
                float zo = bia1[eu*4+3] + zp[3] + zp[640+3] + zp[1280+3] + zp[1920+3];
                float ig = 1.f / (1.f + expf(-zi));
                float fg = 1.f / (1.f + expf(-zf));
                float gg = fmaxf(zg, 0.f);
                float og = 1.f / (1.f + expf(-zo));
                cst = fg * cst + ig * gg;
                float hv = og * fmaxf(cst, 0.f);
                st_cp4(h1b + (size_t)(p & 1) * SLOT
                           + (size_t)(ug * 4 + eu) * NB + bg * 32 + eb, hv);
                __builtin_amdgcn_s_waitcnt(0);
            }
        } else if (tid >= 256 && tid < 384) {
            if (p >= 1) {
                const int t2 = tid - 256, eb = t2 & 31, eu = t2 >> 5;
                const float* zp = zpart + 2560 + eb * 20 + eu * 4;
                float zi = bia2[eu*4+0] + zp[0] + zp[640+0] + zp[1280+0] + zp[1920+0];
                float zf = bia2[eu*4+1] + zp[1] + zp[640+1] + zp[1280+1] + zp[1920+1];
                float zg = bia2[eu*4+2] + zp[2] + zp[640+2] + zp[1280+2] + zp[1920+2];
                float zo = bia2[eu*4+3] + zp[3] + zp[640+3] + zp[1280+3] + zp[1920+3];
                float ig = 1.f / (1.f + expf(-zi));
                float fg = 1.f / (1.f + expf(-zf));
                float gg = fmaxf(zg, 0.f);
                float og = 1.f / (1.f + expf(-zo));
                cst = fg * cst + ig * gg;
                float hv = og * fmaxf(cst, 0.f);
                st_cp4(h2b + (size_t)((p + 1) & 1) * SLOT
                           + (size_t)(ug * 4 + eu) * NB + bg * 32 + eb, hv);
                __builtin_amdgcn_s_waitcnt(0);
            }
        }
        __syncthreads();                                    // B4: publish drained
        if (tid == 0) st_flag(myF, p + 1);
    }
    // final h2 = step 1023 -> slot 1, at ws + 1024 + SLOT
}

// Dense + softmax: one block per batch row. h2 is [H][B]-major.
__global__ __launch_bounds__(256)
void dense_softmax_kernel(const float* __restrict__ h, const float* __restrict__ Wd,
                          const float* __restrict__ bd, float* __restrict__ out)
{
    __shared__ float hsd[HID];
    __shared__ float red[256];
    const int b = blockIdx.x, tid = threadIdx.x;

    hsd[tid] = h[(size_t)tid * NB + b];
    __syncthreads();

    float a0 = 0.f, a1 = 0.f, a2 = 0.f, a3 = 0.f;
    const bool has3 = (tid < DOUT - 768);
    const int c3 = has3 ? (tid + 768) : 0;
    for (int k = 0; k < HID; ++k) {
        const float hk = hsd[k];
        const float* wr = Wd + (size_t)k * DOUT;
        a0 = fmaf(hk, wr[tid],       a0);
        a1 = fmaf(hk, wr[tid + 256], a1);
        a2 = fmaf(hk, wr[tid + 512], a2);
        a3 = fmaf(hk, wr[c3],        a3);
    }
    a0 += bd[tid]; a1 += bd[tid + 256]; a2 += bd[tid + 512];
    if (has3) a3 += bd[tid + 768];

    float m = fmaxf(fmaxf(a0, a1), a2);
    if (has3) m = fmaxf(m, a3);
    red[tid] = m; __syncthreads();
    for (int s = 128; s > 0; s >>= 1) {
        if (tid < s) red[tid] = fmaxf(red[tid], red[tid + s]);
        __syncthreads();
    }
    const float M = red[0];
    __syncthreads();

    float e0 = expf(a0 - M), e1 = expf(a1 - M), e2 = expf(a2 - M);
    float e3 = has3 ? expf(a3 - M) : 0.f;
    red[tid] = e0 + e1 + e2 + e3; __syncthreads();
    for (int s = 128; s > 0; s >>= 1) {
        if (tid < s) red[tid] += red[tid + s];
        __syncthreads();
    }
    const float inv = 1.f / red[0];

    float* o = out + (size_t)b * DOUT;
    o[tid] = e0 * inv;
    o[tid + 256] = e1 * inv;
    o[tid + 512] = e2 * inv;
    if (has3) o[tid + 768] = e3 * inv;
}

extern "C" void kernel_launch(void* const* d_in, const int* in_sizes, int n_in,
                              void* d_out, int out_size, void* d_ws, size_t ws_size,
                              hipStream_t stream)
{
    const float* x  = (const float*)d_in[0];
    const float* W1 = (const float*)d_in[1];
    const float* U1 = (const float*)d_in[2];
    const float* b1 = (const float*)d_in[3];
    const float* W2 = (const float*)d_in[4];
    const float* U2 = (const float*)d_in[5];
    const float* b2 = (const float*)d_in[6];
    const float* Wd = (const float*)d_in[7];
    const float* bd = (const float*)d_in[8];
    float* out = (float*)d_out;
    float* ws  = (float*)d_ws;

    // h1: 2 slots x 32768 floats in d_out (128000 floats), [slot][H][B];
    // fully overwritten by dense_softmax afterwards (which reads only ws).
    float* h1b = out;

    // flag region (ints 0..1023; groups at bg*128) must start at 0
    hipMemsetAsync(ws, 0, 4096, stream);

    hipFuncSetAttribute((const void*)lstm_fused_kernel,
                        hipFuncAttributeMaxDynamicSharedMemorySize, (int)SMEM_BYTES);

    void* args[] = { (void*)&x, (void*)&W1, (void*)&U1, (void*)&b1,
                     (void*)&W2, (void*)&U2, (void*)&b2,
                     (void*)&h1b, (void*)&ws };
    hipError_t err = hipLaunchCooperativeKernel((const void*)lstm_fused_kernel,
                                                dim3(256), dim3(512), args,
                                                (int)SMEM_BYTES, stream);
    if (err != hipSuccess) {
        // a rejected cooperative launch fails SILENTLY without this check.
        // 256 blocks at 1/CU are co-resident by resource constraints, so a
        // plain launch preserves the flag protocol.
        hipLaunchKernelGGL(lstm_fused_kernel, dim3(256), dim3(512),
                           (int)SMEM_BYTES, stream,
                           x, W1, U1, b1, W2, U2, b2, h1b, ws);
    }

    const float* h2final = ws + 1024 + SLOT;   // slot 1 = h2[1023]
    hipLaunchKernelGGL(dense_softmax_kernel, dim3(128), dim3(256), 0, stream,
                       h2final, Wd, bd, out);
}

// Round 2
// 13833.096 us; speedup vs baseline: 1.8366x; 1.8366x over previous
//
#include <hip/hip_runtime.h>
#include <math.h>

static constexpr int T_SEQ = 1024;
static constexpr int DIN = 128;
static constexpr int HID = 256;
static constexpr int DOUT = 1000;
static constexpr int NB = 128;
static constexpr int SLOT = HID * NB;   // 32768 floats per h slot, [H][B]-major

// LDS layout (floats). z buffer is GONE (R10: z lives in registers).
static constexpr int W1STR = 388;              // K=384 + 4
static constexpr int W2STR = 516;              // K=512 + 4
static constexpr int ASTR  = 652;              // [x 0:128 | h1 128:384 | h2 384:640] + 12
static constexpr int OFF_W2 = 16 * W1STR;            // 6208
static constexpr int OFF_A  = OFF_W2 + 16 * W2STR;   // 14464
static constexpr int OFF_B1 = OFF_A + 32 * ASTR;     // 35328
static constexpr int OFF_B2 = OFF_B1 + 16;           // 35344
static constexpr size_t SMEM_BYTES = (size_t)(OFF_B2 + 16) * 4;   // 141,440 B (1 block/CU)

typedef float v4f __attribute__((ext_vector_type(4)));
typedef unsigned long long u64t;

#define SCOPE_AGENT __HIP_MEMORY_SCOPE_AGENT

__device__ __forceinline__ int ld_flag(const int* p) {
    return __hip_atomic_load(p, __ATOMIC_RELAXED, SCOPE_AGENT);
}
__device__ __forceinline__ void st_flag(int* p, int v) {
    __hip_atomic_store(p, v, __ATOMIC_RELAXED, SCOPE_AGENT);
}
// write-through store to the coherence point (producer side only). Consumer
// bulk loads are CACHED: the single post-poll acquire fence invalidates
// L1/L2 first (R4-proven; R9 showed per-wave fences are a ~0.9us/fence
// regression — exactly ONE fence per block per phase).
__device__ __forceinline__ void st_cp4(float* p, float v) {
    __hip_atomic_store(p, v, __ATOMIC_RELAXED, SCOPE_AGENT);
}

union F2U { u64t u; float f[2]; };

__device__ __forceinline__ float dot4(float acc, v4f va, v4f vb) {
    return fmaf(va.x, vb.x, fmaf(va.y, vb.y,
           fmaf(va.z, vb.z, fmaf(va.w, vb.w, acc))));
}

// R10 GEMM tile: 8 batches x 4 cols per thread, k-split 16 WITHIN the wave.
// lane = ks(bits0-3) | cq(bits4-5); wave-in-half = batch-oct bo.
// k chunks interleaved (j*16+ks)*4 floats: each 16-lane ks group reads a
// contiguous 256B run (2 words/bank = conflict-free, m136); the 4 cq groups
// broadcast the same A addresses (free). LDS GEMM traffic 917->688 KB/CU/ph.
template<int NCHUNK, int WSTR>
__device__ __forceinline__ void gemm_tile(float acc[8][4],
                                          const float* __restrict__ Ab,
                                          const float* __restrict__ Wb,
                                          const int ks)
{
    #pragma unroll
    for (int j = 0; j < NCHUNK; ++j) {
        const int ko = (j * 16 + ks) * 4;
        v4f a[8], w[4];
        #pragma unroll
        for (int i = 0; i < 8; ++i) a[i] = *(const v4f*)(Ab + i * ASTR + ko);
        #pragma unroll
        for (int c = 0; c < 4; ++c) w[c] = *(const v4f*)(Wb + c * WSTR + ko);
        #pragma unroll
        for (int i = 0; i < 8; ++i)
            #pragma unroll
            for (int c = 0; c < 4; ++c)
                acc[i][c] = dot4(acc[i][c], a[i], w[c]);
    }
}

// Fold-reduce acc over the 16 ks lanes with ownership halving
// (xor4 -> xor2 -> xor1 -> xor8): 60 shuffles instead of a 128-shuffle full
// butterfly. Lane ks ends owning the COMPLETE z (4 gates) for batch
// bo*8+(ks&7), unit cq. ew + state update + publish happen right here in
// registers: no z LDS buffer, no atomics, no zeroing, no B3 barrier.
// All indices compile-time (rule 20: no runtime-indexed register arrays).
__device__ __forceinline__ void reduce_ew_publish(float acc[8][4], const int ks,
    const float b_i, const float b_f, const float b_g, const float b_o,
    float& cst, float* __restrict__ hb)
{
    #pragma unroll
    for (int i = 0; i < 8; ++i)
        #pragma unroll
        for (int c = 0; c < 4; ++c)
            acc[i][c] += __shfl_xor(acc[i][c], 4);
    float s1[4][4];
    const bool kb2 = (ks & 4) != 0;
    #pragma unroll
    for (int i = 0; i < 4; ++i)
        #pragma unroll
        for (int c = 0; c < 4; ++c)
            s1[i][c] = kb2 ? acc[i + 4][c] : acc[i][c];
    #pragma unroll
    for (int i = 0; i < 4; ++i)
        #pragma unroll
        for (int c = 0; c < 4; ++c)
            s1[i][c] += __shfl_xor(s1[i][c], 2);
    float s2[2][4];
    const bool kb1 = (ks & 2) != 0;
    #pragma unroll
    for (int i = 0; i < 2; ++i)
        #pragma unroll
        for (int c = 0; c < 4; ++c)
            s2[i][c] = kb1 ? s1[i + 2][c] : s1[i][c];
    #pragma unroll
    for (int i = 0; i < 2; ++i)
        #pragma unroll
        for (int c = 0; c < 4; ++c)
            s2[i][c] += __shfl_xor(s2[i][c], 1);
    float z4[4];
    const bool kb0 = (ks & 1) != 0;
    #pragma unroll
    for (int c = 0; c < 4; ++c)
        z4[c] = kb0 ? s2[1][c] : s2[0][c];
    #pragma unroll
    for (int c = 0; c < 4; ++c)
        z4[c] += __shfl_xor(z4[c], 8);

    const float zi = z4[0] + b_i, zf = z4[1] + b_f;
    const float zg = z4[2] + b_g, zo = z4[3] + b_o;
    const float ig = 1.f / (1.f + expf(-zi));
    const float fg = 1.f / (1.f + expf(-zf));
    const float gg = fmaxf(zg, 0.f);
    const float og = 1.f / (1.f + expf(-zo));
    cst = fg * cst + ig * gg;
    const float hv = og * fmaxf(cst, 0.f);
    if (ks < 8) st_cp4(hb + ks, hv);   // lanes ks>=8 are exact mirrors
}

// Fused 2-layer LSTM, 256 blocks x 512 threads, 1 block/CU (LDS 141.4 KB).
// R8 lockstep skeleton (proven): waves 0-3 = layer-1 step p, waves 4-7 =
// layer-2 step p-1. ONE poll + ONE acquire fence per block per phase
// (wave0), cooperative 512-thread staging. R10 changes are GEMM-local:
// 8x4 register tiles with in-wave k-split + in-register z/ew (see above).
// 3 barriers per phase: B1 (post-poll), B2 (post-stage), B4 (publish
// drained / hsA read-write separation across phases).
__global__ __launch_bounds__(512, 2)
void lstm_fused_kernel(const float* __restrict__ x,
                       const float* __restrict__ W1, const float* __restrict__ U1,
                       const float* __restrict__ b1,
                       const float* __restrict__ W2, const float* __restrict__ U2,
                       const float* __restrict__ b2,
                       float* __restrict__ h1b,   // 2*SLOT (d_out scratch), [slot][H][B]
                       float* __restrict__ ws)    // [1024 ints: flags][2*SLOT h2 [H][B]]
{
    extern __shared__ float smem[];
    float* wT1  = smem;
    float* wT2  = smem + OFF_W2;
    float* hsA  = smem + OFF_A;
    float* bia1 = smem + OFF_B1;
    float* bia2 = smem + OFF_B2;

    int*   F   = (int*)ws;          // 4 groups x 128 ints (first 64 used each)
    float* h2b = ws + 1024;

    const int tid = threadIdx.x;
    const int bid = blockIdx.x;
    const int bg  = bid >> 6;       // batch group 0..3 (batches bg*32..+31)
    const int ug  = bid & 63;       // unit group (units ug*4..+3)
    int* grpF = F + bg * 128;
    int* myF  = grpF + ug;

    const int lane = tid & 63;
    const int ks   = lane & 15;     // in-wave k-split index
    const int cq   = lane >> 4;     // col quad = unit 0..3
    const int half = tid >> 8;      // 0: L1 waves, 1: L2 waves
    const int bo   = (tid >> 6) & 3;// wave-in-half = batch oct

    // ---- one-time: both weight tiles (transposed) + biases into LDS ----
    {
        const int hf = tid >> 8;
        const int t  = tid & 255;
        const int K    = hf ? 512 : 384;
        const int len0 = hf ? 256 : 128;
        const float* Wp = hf ? W2 : W1;
        const float* Up = hf ? U2 : U1;
        float* wt = hf ? wT2 : wT1;
        const int wstr = hf ? W2STR : W1STR;
        for (int c = 0; c < 16; ++c) {
            const int col = (c & 3) * HID + ug * 4 + (c >> 2);   // gate-major
            for (int k = t; k < K; k += 256)
                wt[c * wstr + k] = (k < len0) ? Wp[(size_t)k * (4 * HID) + col]
                                              : Up[(size_t)(k - len0) * (4 * HID) + col];
        }
    }
    if (tid < 16)                     bia1[tid] = b1[(tid & 3) * HID + ug * 4 + (tid >> 2)];
    else if (tid >= 256 && tid < 272) { const int t = tid - 256;
                                        bia2[t]  = b2[(t & 3) * HID + ug * 4 + (t >> 2)]; }
    __syncthreads();

    // per-thread persistent state: bias regs (constant all phases) + cell st
    const float* biap = half ? bia2 : bia1;
    const float b_i = biap[cq * 4 + 0], b_f = biap[cq * 4 + 1];
    const float b_g = biap[cq * 4 + 2], b_o = biap[cq * 4 + 3];
    float cst = 0.f;                 // cell state for (batch bo*8+(ks&7), unit cq)

    // publish base for this thread's (unit, batch-oct); +ks per store
    float* const pub1 = h1b + (size_t)(ug * 4 + cq) * NB + bg * 32 + bo * 8;
    float* const pub2 = h2b + (size_t)(ug * 4 + cq) * NB + bg * 32 + bo * 8;

    for (int p = 0; p <= T_SEQ; ++p) {
        // prestage x_p -> hsA[.][0:128)   (read-only input, cached loads)
        if (p < T_SEQ) {
            #pragma unroll
            for (int it = 0; it < 2; ++it) {
                const int idx = tid + it * 512, r = idx >> 5, c4 = idx & 31;
                v4f v = *(const v4f*)(x + ((size_t)(bg * 32 + r) * T_SEQ + p) * DIN + c4 * 4);
                *(v4f*)(hsA + r * ASTR + c4 * 4) = v;
            }
        }
        // wave0: all 64 group blocks finished phase p-1; then invalidate caches.
        // The fence is REQUIRED: consumer h loads below are cached.
        if (tid < 64) {
            for (;;) {
                int a = ld_flag(grpF + tid);
                if (__all(a >= p)) break;
                __builtin_amdgcn_s_sleep(1);
            }
            __builtin_amdgcn_fence(__ATOMIC_ACQUIRE, "agent");
        }
        __syncthreads();                                    // B1

        // stage h1[p-1] -> cols 128:384 and h2[p-2] -> cols 384:640 (transpose)
        // CACHED 8B loads (post-invalidate), cooperative across all 512 thr.
        {
            const u64t* hp1 = (const u64t*)(h1b + (size_t)((p + 1) & 1) * SLOT + bg * 32);
            #pragma unroll
            for (int it = 0; it < 8; ++it) {
                const int idx = tid + it * 512, k = idx >> 4, bb = idx & 15;
                F2U v; v.u = (p == 0) ? 0ull : hp1[(size_t)k * 64 + bb];
                hsA[(bb * 2 + 0) * ASTR + 128 + k] = v.f[0];
                hsA[(bb * 2 + 1) * ASTR + 128 + k] = v.f[1];
            }
            const u64t* hp2 = (const u64t*)(h2b + (size_t)(p & 1) * SLOT + bg * 32);
            #pragma unroll
            for (int it = 0; it < 8; ++it) {
                const int idx = tid + it * 512, k = idx >> 4, bb = idx & 15;
                F2U v; v.u = (p <= 1) ? 0ull : hp2[(size_t)k * 64 + bb];
                hsA[(bb * 2 + 0) * ASTR + 384 + k] = v.f[0];
                hsA[(bb * 2 + 1) * ASTR + 384 + k] = v.f[1];
            }
        }
        __syncthreads();                                    // B2

        // GEMM + in-register reduce/ew/publish per half.
        if (half == 0) {
            if (p < T_SEQ) {
                float acc[8][4] = {};
                gemm_tile<6, W1STR>(acc, hsA + (bo * 8) * ASTR,
                                    wT1 + (cq * 4) * W1STR, ks);
                reduce_ew_publish(acc, ks, b_i, b_f, b_g, b_o, cst,
                                  pub1 + (size_t)(p & 1) * SLOT);
            }
        } else {
            if (p >= 1) {
                float acc[8][4] = {};
                gemm_tile<8, W2STR>(acc, hsA + (bo * 8) * ASTR + 128,
                                    wT2 + (cq * 4) * W2STR, ks);
                reduce_ew_publish(acc, ks, b_i, b_f, b_g, b_o, cst,
                                  pub2 + (size_t)((p + 1) & 1) * SLOT);
            }
        }
        __builtin_amdgcn_s_waitcnt(0);   // drain publish stores pre-B4
        __syncthreads();                                    // B4
        if (tid == 0) st_flag(myF, p + 1);
    }
    // final h2 = step 1023 -> slot 1, at ws + 1024 + SLOT
}

// Dense + softmax: one block per batch row. h2 is [H][B]-major.
__global__ __launch_bounds__(256)
void dense_softmax_kernel(const float* __restrict__ h, const float* __restrict__ Wd,
                          const float* __restrict__ bd, float* __restrict__ out)
{
    __shared__ float hsd[HID];
    __shared__ float red[256];
    const int b = blockIdx.x, tid = threadIdx.x;

    hsd[tid] = h[(size_t)tid * NB + b];
    __syncthreads();

    float a0 = 0.f, a1 = 0.f, a2 = 0.f, a3 = 0.f;
    const bool has3 = (tid < DOUT - 768);
    const int c3 = has3 ? (tid + 768) : 0;
    for (int k = 0; k < HID; ++k) {
        const float hk = hsd[k];
        const float* wr = Wd + (size_t)k * DOUT;
        a0 = fmaf(hk, wr[tid],       a0);
        a1 = fmaf(hk, wr[tid + 256], a1);
        a2 = fmaf(hk, wr[tid + 512], a2);
        a3 = fmaf(hk, wr[c3],        a3);
    }
    a0 += bd[tid]; a1 += bd[tid + 256]; a2 += bd[tid + 512];
    if (has3) a3 += bd[tid + 768];

    float m = fmaxf(fmaxf(a0, a1), a2);
    if (has3) m = fmaxf(m, a3);
    red[tid] = m; __syncthreads();
    for (int s = 128; s > 0; s >>= 1) {
        if (tid < s) red[tid] = fmaxf(red[tid], red[tid + s]);
        __syncthreads();
    }
    const float M = red[0];
    __syncthreads();

    float e0 = expf(a0 - M), e1 = expf(a1 - M), e2 = expf(a2 - M);
    float e3 = has3 ? expf(a3 - M) : 0.f;
    red[tid] = e0 + e1 + e2 + e3; __syncthreads();
    for (int s = 128; s > 0; s >>= 1) {
        if (tid < s) red[tid] += red[tid + s];
        __syncthreads();
    }
    const float inv = 1.f / red[0];

    float* o = out + (size_t)b * DOUT;
    o[tid] = e0 * inv;
    o[tid + 256] = e1 * inv;
    o[tid + 512] = e2 * inv;
    if (has3) o[tid + 768] = e3 * inv;
}

extern "C" void kernel_launch(void* const* d_in, const int* in_sizes, int n_in,
                              void* d_out, int out_size, void* d_ws, size_t ws_size,
                              hipStream_t stream)
{
    const float* x  = (const float*)d_in[0];
    const float* W1 = (const float*)d_in[1];
    const float* U1 = (const float*)d_in[2];
    const float* b1 = (const float*)d_in[3];
    const float* W2 = (const float*)d_in[4];
    const float* U2 = (const float*)d_in[5];
    const float* b2 = (const float*)d_in[6];
    const float* Wd = (const float*)d_in[7];
    const float* bd = (const float*)d_in[8];
    float* out = (float*)d_out;
    float* ws  = (float*)d_ws;

    // h1: 2 slots x 32768 floats in d_out (128000 floats), [slot][H][B];
    // fully overwritten by dense_softmax afterwards (which reads only ws).
    float* h1b = out;

    // flag region (ints 0..1023; groups at bg*128) must start at 0
    hipMemsetAsync(ws, 0, 4096, stream);

    hipFuncSetAttribute((const void*)lstm_fused_kernel,
                        hipFuncAttributeMaxDynamicSharedMemorySize, (int)SMEM_BYTES);

    void* args[] = { (void*)&x, (void*)&W1, (void*)&U1, (void*)&b1,
                     (void*)&W2, (void*)&U2, (void*)&b2,
                     (void*)&h1b, (void*)&ws };
    hipError_t err = hipLaunchCooperativeKernel((const void*)lstm_fused_kernel,
                                                dim3(256), dim3(512), args,
                                                (int)SMEM_BYTES, stream);
    if (err != hipSuccess) {
        // a rejected cooperative launch fails SILENTLY without this check.
        // 256 blocks at 1/CU are co-resident by resource constraints, so a
        // plain launch preserves the flag protocol.
        hipLaunchKernelGGL(lstm_fused_kernel, dim3(256), dim3(512),
                           (int)SMEM_BYTES, stream,
                           x, W1, U1, b1, W2, U2, b2, h1b, ws);
    }

    const float* h2final = ws + 1024 + SLOT;   // slot 1 = h2[1023]
    hipLaunchKernelGGL(dense_softmax_kernel, dim3(128), dim3(256), 0, stream,
                       h2final, Wd, bd, out);
}

// Round 3
// 13696.506 us; speedup vs baseline: 1.8549x; 1.0100x over previous
//
#include <hip/hip_runtime.h>
#include <math.h>

static constexpr int T_SEQ = 1024;
static constexpr int DIN = 128;
static constexpr int HID = 256;
static constexpr int DOUT = 1000;
static constexpr int NB = 128;
static constexpr int SLOT = HID * NB;   // 32768 floats per h slot, [H][B]-major

// LDS layout (floats). z buffer is GONE (R10: z lives in registers).
static constexpr int W1STR = 388;              // K=384 + 4
static constexpr int W2STR = 516;              // K=512 + 4
static constexpr int ASTR  = 652;              // [x 0:128 | h1 128:384 | h2 384:640] + 12
static constexpr int OFF_W2 = 16 * W1STR;            // 6208
static constexpr int OFF_A  = OFF_W2 + 16 * W2STR;   // 14464
static constexpr int OFF_B1 = OFF_A + 32 * ASTR;     // 35328
static constexpr int OFF_B2 = OFF_B1 + 16;           // 35344
static constexpr size_t SMEM_BYTES = (size_t)(OFF_B2 + 16) * 4;   // 141,440 B (1 block/CU)

typedef float v4f __attribute__((ext_vector_type(4)));
typedef unsigned long long u64t;

#define SCOPE_AGENT __HIP_MEMORY_SCOPE_AGENT

__device__ __forceinline__ int ld_flag(const int* p) {
    return __hip_atomic_load(p, __ATOMIC_RELAXED, SCOPE_AGENT);
}
__device__ __forceinline__ void st_flag(int* p, int v) {
    __hip_atomic_store(p, v, __ATOMIC_RELAXED, SCOPE_AGENT);
}
// write-through store to the coherence point (producer side only). Consumer
// bulk loads are CACHED: the single post-poll acquire fence invalidates
// L1/L2 first (R4-proven; R9 showed per-wave fences are a ~0.9us/fence
// regression — exactly ONE fence per block per phase).
__device__ __forceinline__ void st_cp4(float* p, float v) {
    __hip_atomic_store(p, v, __ATOMIC_RELAXED, SCOPE_AGENT);
}

union F2U { u64t u; float f[2]; };

__device__ __forceinline__ float dot4(float acc, v4f va, v4f vb) {
    return fmaf(va.x, vb.x, fmaf(va.y, vb.y,
           fmaf(va.z, vb.z, fmaf(va.w, vb.w, acc))));
}

// R10 GEMM tile: 8 batches x 4 cols per thread, k-split 16 WITHIN the wave.
// lane = ks(bits0-3) | cq(bits4-5); wave-in-half = batch-oct bo.
// k chunks interleaved (j*16+ks)*4 floats: each 16-lane ks group reads a
// contiguous 256B run (2 words/bank = free, m136); the 4 cq groups
// broadcast the same A addresses (free). LDS GEMM traffic 917->688 KB/CU/ph.
template<int NCHUNK, int WSTR>
__device__ __forceinline__ void gemm_tile(float acc[8][4],
                                          const float* __restrict__ Ab,
                                          const float* __restrict__ Wb,
                                          const int ks)
{
    #pragma unroll
    for (int j = 0; j < NCHUNK; ++j) {
        const int ko = (j * 16 + ks) * 4;
        v4f a[8], w[4];
        #pragma unroll
        for (int i = 0; i < 8; ++i) a[i] = *(const v4f*)(Ab + i * ASTR + ko);
        #pragma unroll
        for (int c = 0; c < 4; ++c) w[c] = *(const v4f*)(Wb + c * WSTR + ko);
        #pragma unroll
        for (int i = 0; i < 8; ++i)
            #pragma unroll
            for (int c = 0; c < 4; ++c)
                acc[i][c] = dot4(acc[i][c], a[i], w[c]);
    }
}

// Fold-reduce acc over the 16 ks lanes with ownership halving
// (xor4 -> xor2 -> xor1 -> xor8): 60 shuffles instead of a 128-shuffle full
// butterfly. Lane ks ends owning the COMPLETE z (4 gates) for batch
// bo*8+(ks&7), unit cq. ew + state update + publish happen right here in
// registers: no z LDS buffer, no atomics, no zeroing, no B3 barrier.
// All indices compile-time (rule 20: no runtime-indexed register arrays).
__device__ __forceinline__ void reduce_ew_publish(float acc[8][4], const int ks,
    const float b_i, const float b_f, const float b_g, const float b_o,
    float& cst, float* __restrict__ hb)
{
    #pragma unroll
    for (int i = 0; i < 8; ++i)
        #pragma unroll
        for (int c = 0; c < 4; ++c)
            acc[i][c] += __shfl_xor(acc[i][c], 4);
    float s1[4][4];
    const bool kb2 = (ks & 4) != 0;
    #pragma unroll
    for (int i = 0; i < 4; ++i)
        #pragma unroll
        for (int c = 0; c < 4; ++c)
            s1[i][c] = kb2 ? acc[i + 4][c] : acc[i][c];
    #pragma unroll
    for (int i = 0; i < 4; ++i)
        #pragma unroll
        for (int c = 0; c < 4; ++c)
            s1[i][c] += __shfl_xor(s1[i][c], 2);
    float s2[2][4];
    const bool kb1 = (ks & 2) != 0;
    #pragma unroll
    for (int i = 0; i < 2; ++i)
        #pragma unroll
        for (int c = 0; c < 4; ++c)
            s2[i][c] = kb1 ? s1[i + 2][c] : s1[i][c];
    #pragma unroll
    for (int i = 0; i < 2; ++i)
        #pragma unroll
        for (int c = 0; c < 4; ++c)
            s2[i][c] += __shfl_xor(s2[i][c], 1);
    float z4[4];
    const bool kb0 = (ks & 1) != 0;
    #pragma unroll
    for (int c = 0; c < 4; ++c)
        z4[c] = kb0 ? s2[1][c] : s2[0][c];
    #pragma unroll
    for (int c = 0; c < 4; ++c)
        z4[c] += __shfl_xor(z4[c], 8);

    const float zi = z4[0] + b_i, zf = z4[1] + b_f;
    const float zg = z4[2] + b_g, zo = z4[3] + b_o;
    const float ig = 1.f / (1.f + expf(-zi));
    const float fg = 1.f / (1.f + expf(-zf));
    const float gg = fmaxf(zg, 0.f);
    const float og = 1.f / (1.f + expf(-zo));
    cst = fg * cst + ig * gg;
    const float hv = og * fmaxf(cst, 0.f);
    if (ks < 8) st_cp4(hb + ks, hv);   // lanes ks>=8 are exact mirrors
}

// Fused 2-layer LSTM, 256 blocks x 512 threads, 1 block/CU (LDS 141.4 KB).
// R8 lockstep skeleton (proven): waves 0-3 = layer-1 step p, waves 4-7 =
// layer-2 step p-1. ONE poll + ONE acquire fence per block per phase
// (wave0), cooperative 512-thread staging. R10: 8x4 register tiles with
// in-wave k-split + in-register z/ew. R11: NO min-waves launch-bound —
// R10's (512,2) capped VGPRs at 128 and forced scratch spills; the
// per-phase acquire fence then flushed the dirty spill lines every phase
// (WRITE_SIZE 270MB -> 30.9GB). LDS already pins 1 block/CU (8 waves =
// 2/SIMD, hardware allows 256 VGPRs), so the cap bought nothing.
// 3 barriers per phase: B1 (post-poll), B2 (post-stage), B4 (publish
// drained / hsA read-write separation across phases).
__global__ __launch_bounds__(512)
void lstm_fused_kernel(const float* __restrict__ x,
                       const float* __restrict__ W1, const float* __restrict__ U1,
                       const float* __restrict__ b1,
                       const float* __restrict__ W2, const float* __restrict__ U2,
                       const float* __restrict__ b2,
                       float* __restrict__ h1b,   // 2*SLOT (d_out scratch), [slot][H][B]
                       float* __restrict__ ws)    // [1024 ints: flags][2*SLOT h2 [H][B]]
{
    extern __shared__ float smem[];
    float* wT1  = smem;
    float* wT2  = smem + OFF_W2;
    float* hsA  = smem + OFF_A;
    float* bia1 = smem + OFF_B1;
    float* bia2 = smem + OFF_B2;

    int*   F   = (int*)ws;          // 4 groups x 128 ints (first 64 used each)
    float* h2b = ws + 1024;

    const int tid = threadIdx.x;
    const int bid = blockIdx.x;
    const int bg  = bid >> 6;       // batch group 0..3 (batches bg*32..+31)
    const int ug  = bid & 63;       // unit group (units ug*4..+3)
    int* grpF = F + bg * 128;
    int* myF  = grpF + ug;

    const int lane = tid & 63;
    const int ks   = lane & 15;     // in-wave k-split index
    const int cq   = lane >> 4;     // col quad = unit 0..3
    const int half = tid >> 8;      // 0: L1 waves, 1: L2 waves
    const int bo   = (tid >> 6) & 3;// wave-in-half = batch oct

    // ---- one-time: both weight tiles (transposed) + biases into LDS ----
    {
        const int hf = tid >> 8;
        const int t  = tid & 255;
        const int K    = hf ? 512 : 384;
        const int len0 = hf ? 256 : 128;
        const float* Wp = hf ? W2 : W1;
        const float* Up = hf ? U2 : U1;
        float* wt = hf ? wT2 : wT1;
        const int wstr = hf ? W2STR : W1STR;
        for (int c = 0; c < 16; ++c) {
            const int col = (c & 3) * HID + ug * 4 + (c >> 2);   // gate-major
            for (int k = t; k < K; k += 256)
                wt[c * wstr + k] = (k < len0) ? Wp[(size_t)k * (4 * HID) + col]
                                              : Up[(size_t)(k - len0) * (4 * HID) + col];
        }
    }
    if (tid < 16)                     bia1[tid] = b1[(tid & 3) * HID + ug * 4 + (tid >> 2)];
    else if (tid >= 256 && tid < 272) { const int t = tid - 256;
                                        bia2[t]  = b2[(t & 3) * HID + ug * 4 + (t >> 2)]; }
    __syncthreads();

    // per-thread persistent state: bias regs (constant all phases) + cell st
    const float* biap = half ? bia2 : bia1;
    const float b_i = biap[cq * 4 + 0], b_f = biap[cq * 4 + 1];
    const float b_g = biap[cq * 4 + 2], b_o = biap[cq * 4 + 3];
    float cst = 0.f;                 // cell state for (batch bo*8+(ks&7), unit cq)

    // publish base for this thread's (unit, batch-oct); +ks per store
    float* const pub1 = h1b + (size_t)(ug * 4 + cq) * NB + bg * 32 + bo * 8;
    float* const pub2 = h2b + (size_t)(ug * 4 + cq) * NB + bg * 32 + bo * 8;

    for (int p = 0; p <= T_SEQ; ++p) {
        // prestage x_p -> hsA[.][0:128)   (read-only input, cached loads)
        if (p < T_SEQ) {
            #pragma unroll
            for (int it = 0; it < 2; ++it) {
                const int idx = tid + it * 512, r = idx >> 5, c4 = idx & 31;
                v4f v = *(const v4f*)(x + ((size_t)(bg * 32 + r) * T_SEQ + p) * DIN + c4 * 4);
                *(v4f*)(hsA + r * ASTR + c4 * 4) = v;
            }
        }
        // wave0: all 64 group blocks finished phase p-1; then invalidate caches.
        // The fence is REQUIRED: consumer h loads below are cached.
        if (tid < 64) {
            for (;;) {
                int a = ld_flag(grpF + tid);
                if (__all(a >= p)) break;
                __builtin_amdgcn_s_sleep(1);
            }
            __builtin_amdgcn_fence(__ATOMIC_ACQUIRE, "agent");
        }
        __syncthreads();                                    // B1

        // stage h1[p-1] -> cols 128:384 and h2[p-2] -> cols 384:640 (transpose)
        // CACHED 8B loads (post-invalidate), cooperative across all 512 thr.
        {
            const u64t* hp1 = (const u64t*)(h1b + (size_t)((p + 1) & 1) * SLOT + bg * 32);
            #pragma unroll
            for (int it = 0; it < 8; ++it) {
                const int idx = tid + it * 512, k = idx >> 4, bb = idx & 15;
                F2U v; v.u = (p == 0) ? 0ull : hp1[(size_t)k * 64 + bb];
                hsA[(bb * 2 + 0) * ASTR + 128 + k] = v.f[0];
                hsA[(bb * 2 + 1) * ASTR + 128 + k] = v.f[1];
            }
            const u64t* hp2 = (const u64t*)(h2b + (size_t)(p & 1) * SLOT + bg * 32);
            #pragma unroll
            for (int it = 0; it < 8; ++it) {
                const int idx = tid + it * 512, k = idx >> 4, bb = idx & 15;
                F2U v; v.u = (p <= 1) ? 0ull : hp2[(size_t)k * 64 + bb];
                hsA[(bb * 2 + 0) * ASTR + 384 + k] = v.f[0];
                hsA[(bb * 2 + 1) * ASTR + 384 + k] = v.f[1];
            }
        }
        __syncthreads();                                    // B2

        // GEMM + in-register reduce/ew/publish per half.
        if (half == 0) {
            if (p < T_SEQ) {
                float acc[8][4] = {};
                gemm_tile<6, W1STR>(acc, hsA + (bo * 8) * ASTR,
                                    wT1 + (cq * 4) * W1STR, ks);
                reduce_ew_publish(acc, ks, b_i, b_f, b_g, b_o, cst,
                                  pub1 + (size_t)(p & 1) * SLOT);
            }
        } else {
            if (p >= 1) {
                float acc[8][4] = {};
                gemm_tile<8, W2STR>(acc, hsA + (bo * 8) * ASTR + 128,
                                    wT2 + (cq * 4) * W2STR, ks);
                reduce_ew_publish(acc, ks, b_i, b_f, b_g, b_o, cst,
                                  pub2 + (size_t)((p + 1) & 1) * SLOT);
            }
        }
        __builtin_amdgcn_s_waitcnt(0);   // drain publish stores pre-B4
        __syncthreads();                                    // B4
        if (tid == 0) st_flag(myF, p + 1);
    }
    // final h2 = step 1023 -> slot 1, at ws + 1024 + SLOT
}

// Dense + softmax: one block per batch row. h2 is [H][B]-major.
__global__ __launch_bounds__(256)
void dense_softmax_kernel(const float* __restrict__ h, const float* __restrict__ Wd,
                          const float* __restrict__ bd, float* __restrict__ out)
{
    __shared__ float hsd[HID];
    __shared__ float red[256];
    const int b = blockIdx.x, tid = threadIdx.x;

    hsd[tid] = h[(size_t)tid * NB + b];
    __syncthreads();

    float a0 = 0.f, a1 = 0.f, a2 = 0.f, a3 = 0.f;
    const bool has3 = (tid < DOUT - 768);
    const int c3 = has3 ? (tid + 768) : 0;
    for (int k = 0; k < HID; ++k) {
        const float hk = hsd[k];
        const float* wr = Wd + (size_t)k * DOUT;
        a0 = fmaf(hk, wr[tid],       a0);
        a1 = fmaf(hk, wr[tid + 256], a1);
        a2 = fmaf(hk, wr[tid + 512], a2);
        a3 = fmaf(hk, wr[c3],        a3);
    }
    a0 += bd[tid]; a1 += bd[tid + 256]; a2 += bd[tid + 512];
    if (has3) a3 += bd[tid + 768];

    float m = fmaxf(fmaxf(a0, a1), a2);
    if (has3) m = fmaxf(m, a3);
    red[tid] = m; __syncthreads();
    for (int s = 128; s > 0; s >>= 1) {
        if (tid < s) red[tid] = fmaxf(red[tid], red[tid + s]);
        __syncthreads();
    }
    const float M = red[0];
    __syncthreads();

    float e0 = expf(a0 - M), e1 = expf(a1 - M), e2 = expf(a2 - M);
    float e3 = has3 ? expf(a3 - M) : 0.f;
    red[tid] = e0 + e1 + e2 + e3; __syncthreads();
    for (int s = 128; s > 0; s >>= 1) {
        if (tid < s) red[tid] += red[tid + s];
        __syncthreads();
    }
    const float inv = 1.f / red[0];

    float* o = out + (size_t)b * DOUT;
    o[tid] = e0 * inv;
    o[tid + 256] = e1 * inv;
    o[tid + 512] = e2 * inv;
    if (has3) o[tid + 768] = e3 * inv;
}

extern "C" void kernel_launch(void* const* d_in, const int* in_sizes, int n_in,
                              void* d_out, int out_size, void* d_ws, size_t ws_size,
                              hipStream_t stream)
{
    const float* x  = (const float*)d_in[0];
    const float* W1 = (const float*)d_in[1];
    const float* U1 = (const float*)d_in[2];
    const float* b1 = (const float*)d_in[3];
    const float* W2 = (const float*)d_in[4];
    const float* U2 = (const float*)d_in[5];
    const float* b2 = (const float*)d_in[6];
    const float* Wd = (const float*)d_in[7];
    const float* bd = (const float*)d_in[8];
    float* out = (float*)d_out;
    float* ws  = (float*)d_ws;

    // h1: 2 slots x 32768 floats in d_out (128000 floats), [slot][H][B];
    // fully overwritten by dense_softmax afterwards (which reads only ws).
    float* h1b = out;

    // flag region (ints 0..1023; groups at bg*128) must start at 0
    hipMemsetAsync(ws, 0, 4096, stream);

    hipFuncSetAttribute((const void*)lstm_fused_kernel,
                        hipFuncAttributeMaxDynamicSharedMemorySize, (int)SMEM_BYTES);

    void* args[] = { (void*)&x, (void*)&W1, (void*)&U1, (void*)&b1,
                     (void*)&W2, (void*)&U2, (void*)&b2,
                     (void*)&h1b, (void*)&ws };
    hipError_t err = hipLaunchCooperativeKernel((const void*)lstm_fused_kernel,
                                                dim3(256), dim3(512), args,
                                                (int)SMEM_BYTES, stream);
    if (err != hipSuccess) {
        // a rejected cooperative launch fails SILENTLY without this check.
        // 256 blocks at 1/CU are co-resident by resource constraints, so a
        // plain launch preserves the flag protocol.
        hipLaunchKernelGGL(lstm_fused_kernel, dim3(256), dim3(512),
                           (int)SMEM_BYTES, stream,
                           x, W1, U1, b1, W2, U2, b2, h1b, ws);
    }

    const float* h2final = ws + 1024 + SLOT;   // slot 1 = h2[1023]
    hipLaunchKernelGGL(dense_softmax_kernel, dim3(128), dim3(256), 0, stream,
                       h2final, Wd, bd, out);
}